// Round 4
// baseline (76.301 us; speedup 1.0000x reference)
//
#include <hip/hip_runtime.h>
#include <math.h>

#define NCOLS 4096
#define NC4   1024                // float4 columns per row
#define TPB   1024
#define ROWS_PER_BLOCK 16         // 512 blocks for B=8192 -> 2 blocks/CU

__device__ __forceinline__ float softplus_f(float x) {
    // numerically stable: max(x,0) + log1p(exp(-|x|))
    return fmaxf(x, 0.0f) + log1pf(expf(-fabsf(x)));
}

// ---------------------------------------------------------------------------
// Fused kernel: block b owns contiguous rows [b*16, b*16+16). Thread t owns
// float4 column t (inv_var computed once from sigma). Unroll 4 rows -> 8
// independent 16B loads in flight; block's working set = two contiguous
// 64 KB chunks per step (sequential DRAM/L3 streams).
// Last-arriving block (device-scope ticket) reduces the 512 partials,
// computes logdet inline, writes the scalar. No second kernel launch.
// ---------------------------------------------------------------------------
__global__ __launch_bounds__(TPB, 8) void gauss_fused_kernel(
        const float4* __restrict__ pred,
        const float4* __restrict__ gt,
        const float* __restrict__ sigma,
        float* __restrict__ partials,
        unsigned int* __restrict__ counter,
        float* __restrict__ out,
        int B, int nblocks) {
    const int c4 = threadIdx.x;                    // 0..1023
    const int r0 = blockIdx.x * ROWS_PER_BLOCK;

    // per-thread inv_var (once)
    const float4 s4 = reinterpret_cast<const float4*>(sigma)[c4];
    float4 iv;
    iv.x = 1.0f / softplus_f(s4.x);
    iv.y = 1.0f / softplus_f(s4.y);
    iv.z = 1.0f / softplus_f(s4.z);
    iv.w = 1.0f / softplus_f(s4.w);

    float a0 = 0.0f, a1 = 0.0f, a2 = 0.0f, a3 = 0.0f;

    const int rend = (r0 + ROWS_PER_BLOCK < B) ? ROWS_PER_BLOCK : (B - r0);
    int r = 0;
    for (; r + 3 < rend; r += 4) {
        const size_t i0 = (size_t)(r0 + r) * NC4 + c4;
        const float4 p0 = pred[i0 + 0 * NC4], g0 = gt[i0 + 0 * NC4];
        const float4 p1 = pred[i0 + 1 * NC4], g1 = gt[i0 + 1 * NC4];
        const float4 p2 = pred[i0 + 2 * NC4], g2 = gt[i0 + 2 * NC4];
        const float4 p3 = pred[i0 + 3 * NC4], g3 = gt[i0 + 3 * NC4];

        float dx, dy, dz, dw;
        dx = g0.x - p0.x; dy = g0.y - p0.y; dz = g0.z - p0.z; dw = g0.w - p0.w;
        a0 += dx * dx * iv.x + dy * dy * iv.y + dz * dz * iv.z + dw * dw * iv.w;
        dx = g1.x - p1.x; dy = g1.y - p1.y; dz = g1.z - p1.z; dw = g1.w - p1.w;
        a1 += dx * dx * iv.x + dy * dy * iv.y + dz * dz * iv.z + dw * dw * iv.w;
        dx = g2.x - p2.x; dy = g2.y - p2.y; dz = g2.z - p2.z; dw = g2.w - p2.w;
        a2 += dx * dx * iv.x + dy * dy * iv.y + dz * dz * iv.z + dw * dw * iv.w;
        dx = g3.x - p3.x; dy = g3.y - p3.y; dz = g3.z - p3.z; dw = g3.w - p3.w;
        a3 += dx * dx * iv.x + dy * dy * iv.y + dz * dz * iv.z + dw * dw * iv.w;
    }
    for (; r < rend; ++r) {  // generic tail (empty for B=8192)
        const size_t i = (size_t)(r0 + r) * NC4 + c4;
        const float4 p = pred[i], g = gt[i];
        float dx = g.x - p.x, dy = g.y - p.y, dz = g.z - p.z, dw = g.w - p.w;
        a0 += dx * dx * iv.x + dy * dy * iv.y + dz * dz * iv.z + dw * dw * iv.w;
    }

    float acc = (a0 + a1) + (a2 + a3);

    // wave (64-lane) shuffle reduction
    for (int off = 32; off > 0; off >>= 1)
        acc += __shfl_down(acc, off, 64);

    __shared__ float wred[16];
    __shared__ unsigned int ticket_s;
    const int wave = threadIdx.x >> 6;
    const int lane = threadIdx.x & 63;
    if (lane == 0) wred[wave] = acc;
    __syncthreads();
    if (threadIdx.x == 0) {
        float s = 0.0f;
        for (int w = 0; w < 16; ++w) s += wred[w];
        // agent-scope release store: visible across XCDs
        __hip_atomic_store(&partials[blockIdx.x], s,
                           __ATOMIC_RELEASE, __HIP_MEMORY_SCOPE_AGENT);
        ticket_s = __hip_atomic_fetch_add(counter, 1u,
                                          __ATOMIC_ACQ_REL, __HIP_MEMORY_SCOPE_AGENT);
    }
    __syncthreads();

    if (ticket_s != (unsigned int)(nblocks - 1)) return;

    // ---- last-arriving block: final reduction (deterministic order) ----
    const int t = threadIdx.x;
    float q = 0.0f;
    for (int i = t; i < nblocks; i += TPB)
        q += __hip_atomic_load(&partials[i], __ATOMIC_ACQUIRE,
                               __HIP_MEMORY_SCOPE_AGENT);

    float ld = 0.0f;
    for (int n = t; n < NCOLS; n += TPB)
        ld += logf(softplus_f(sigma[n]));

    for (int off = 32; off > 0; off >>= 1) {
        q  += __shfl_down(q, off, 64);
        ld += __shfl_down(ld, off, 64);
    }

    __shared__ float wq[16], wl[16];
    if (lane == 0) { wq[wave] = q; wl[wave] = ld; }
    __syncthreads();
    if (t == 0) {
        float quad = 0.0f, logdet = 0.0f;
        for (int w = 0; w < 16; ++w) { quad += wq[w]; logdet += wl[w]; }
        const double LOG_2PI = 1.8378770664093453;
        out[0] = (float)(0.5 * ((double)quad +
                                 (double)B * ((double)logdet +
                                              (double)NCOLS * LOG_2PI)));
    }
}

extern "C" void kernel_launch(void* const* d_in, const int* in_sizes, int n_in,
                              void* d_out, int out_size, void* d_ws, size_t ws_size,
                              hipStream_t stream) {
    const float* pred  = (const float*)d_in[0];
    const float* gt    = (const float*)d_in[1];
    const float* sigma = (const float*)d_in[2];
    float* out = (float*)d_out;

    float* partials       = (float*)d_ws;                  // nblocks floats
    unsigned int* counter = (unsigned int*)((char*)d_ws + 64 * 1024);

    const int B = in_sizes[0] / NCOLS;                              // 8192
    const int nblocks = (B + ROWS_PER_BLOCK - 1) / ROWS_PER_BLOCK;  // 512

    hipMemsetAsync(counter, 0, sizeof(unsigned int), stream);
    gauss_fused_kernel<<<nblocks, TPB, 0, stream>>>(
        (const float4*)pred, (const float4*)gt, sigma,
        partials, counter, out, B, nblocks);
}

// Round 5
// 48.875 us; speedup vs baseline: 1.5611x; 1.5611x over previous
//
#include <hip/hip_runtime.h>
#include <math.h>

#define NCOLS 4096
#define NC4   1024                // float4 columns per row
#define TPB   1024                // one float4-row per block pass
#define ROWS_PER_BLOCK 16         // 512 blocks for B=8192 -> 2 blocks/CU

typedef float f32x4 __attribute__((ext_vector_type(4)));

__device__ __forceinline__ float softplus_f(float x) {
    // numerically stable: max(x,0) + log1p(exp(-|x|))
    return fmaxf(x, 0.0f) + log1pf(expf(-fabsf(x)));
}

// nontemporal 16B load: nt flag -> no L1/L2 allocation (MALL/L3 is
// memory-side and still caches/serves these on warm replays)
__device__ __forceinline__ f32x4 ntload4(const f32x4* p) {
    return __builtin_nontemporal_load(p);
}

// ---------------------------------------------------------------------------
// quad: block b owns contiguous rows [b*16, b*16+16). Thread t owns float4
// column t (inv_var computed once from sigma). Unroll 4 rows -> 8
// independent nontemporal 16B loads in flight; block working set = two
// contiguous 64 KB chunks per step (sequential DRAM/L3 streams, no L2
// allocate/evict churn).
// ---------------------------------------------------------------------------
__global__ __launch_bounds__(TPB, 8) void gauss_quad_kernel(
        const f32x4* __restrict__ pred,
        const f32x4* __restrict__ gt,
        const float* __restrict__ sigma,
        float* __restrict__ partials,
        int B) {
    const int c4 = threadIdx.x;                    // 0..1023
    const int r0 = blockIdx.x * ROWS_PER_BLOCK;

    // per-thread inv_var (once; sigma stays in cache - normal load)
    const f32x4 s4 = reinterpret_cast<const f32x4*>(sigma)[c4];
    f32x4 iv;
    iv.x = 1.0f / softplus_f(s4.x);
    iv.y = 1.0f / softplus_f(s4.y);
    iv.z = 1.0f / softplus_f(s4.z);
    iv.w = 1.0f / softplus_f(s4.w);

    float a0 = 0.0f, a1 = 0.0f, a2 = 0.0f, a3 = 0.0f;

    const int rend = (r0 + ROWS_PER_BLOCK < B) ? ROWS_PER_BLOCK : (B - r0);
    int r = 0;
    for (; r + 3 < rend; r += 4) {
        const size_t i0 = (size_t)(r0 + r) * NC4 + c4;
        const f32x4 p0 = ntload4(pred + i0 + 0 * NC4), g0 = ntload4(gt + i0 + 0 * NC4);
        const f32x4 p1 = ntload4(pred + i0 + 1 * NC4), g1 = ntload4(gt + i0 + 1 * NC4);
        const f32x4 p2 = ntload4(pred + i0 + 2 * NC4), g2 = ntload4(gt + i0 + 2 * NC4);
        const f32x4 p3 = ntload4(pred + i0 + 3 * NC4), g3 = ntload4(gt + i0 + 3 * NC4);

        float dx, dy, dz, dw;
        dx = g0.x - p0.x; dy = g0.y - p0.y; dz = g0.z - p0.z; dw = g0.w - p0.w;
        a0 += dx * dx * iv.x + dy * dy * iv.y + dz * dz * iv.z + dw * dw * iv.w;
        dx = g1.x - p1.x; dy = g1.y - p1.y; dz = g1.z - p1.z; dw = g1.w - p1.w;
        a1 += dx * dx * iv.x + dy * dy * iv.y + dz * dz * iv.z + dw * dw * iv.w;
        dx = g2.x - p2.x; dy = g2.y - p2.y; dz = g2.z - p2.z; dw = g2.w - p2.w;
        a2 += dx * dx * iv.x + dy * dy * iv.y + dz * dz * iv.z + dw * dw * iv.w;
        dx = g3.x - p3.x; dy = g3.y - p3.y; dz = g3.z - p3.z; dw = g3.w - p3.w;
        a3 += dx * dx * iv.x + dy * dy * iv.y + dz * dz * iv.z + dw * dw * iv.w;
    }
    for (; r < rend; ++r) {  // generic tail (empty for B=8192)
        const size_t i = (size_t)(r0 + r) * NC4 + c4;
        const f32x4 p = ntload4(pred + i), g = ntload4(gt + i);
        float dx = g.x - p.x, dy = g.y - p.y, dz = g.z - p.z, dw = g.w - p.w;
        a0 += dx * dx * iv.x + dy * dy * iv.y + dz * dz * iv.z + dw * dw * iv.w;
    }

    float acc = (a0 + a1) + (a2 + a3);

    // wave (64-lane) shuffle reduction
    for (int off = 32; off > 0; off >>= 1)
        acc += __shfl_down(acc, off, 64);

    __shared__ float wred[16];
    const int wave = threadIdx.x >> 6;
    const int lane = threadIdx.x & 63;
    if (lane == 0) wred[wave] = acc;
    __syncthreads();
    if (threadIdx.x == 0) {
        float s = 0.0f;
        for (int w = 0; w < 16; ++w) s += wred[w];
        partials[blockIdx.x] = s;
    }
}

// ---------------------------------------------------------------------------
// finalize: one block. Reduce nblocks partials + logdet(sigma) inline.
// ---------------------------------------------------------------------------
__global__ __launch_bounds__(1024) void gauss_finalize_kernel(
        const float* __restrict__ partials,
        const float* __restrict__ sigma,
        float* __restrict__ out, int B, int nblocks) {
    const int t = threadIdx.x;

    float q = 0.0f;
    for (int i = t; i < nblocks; i += 1024) q += partials[i];

    float ld = 0.0f;
    for (int n = t; n < NCOLS; n += 1024) ld += logf(softplus_f(sigma[n]));

    for (int off = 32; off > 0; off >>= 1) {
        q  += __shfl_down(q, off, 64);
        ld += __shfl_down(ld, off, 64);
    }

    __shared__ float wq[16], wl[16];
    const int wave = t >> 6;
    const int lane = t & 63;
    if (lane == 0) { wq[wave] = q; wl[wave] = ld; }
    __syncthreads();
    if (t == 0) {
        float quad = 0.0f, logdet = 0.0f;
        for (int w = 0; w < 16; ++w) { quad += wq[w]; logdet += wl[w]; }
        const double LOG_2PI = 1.8378770664093453;
        out[0] = (float)(0.5 * ((double)quad +
                                 (double)B * ((double)logdet +
                                              (double)NCOLS * LOG_2PI)));
    }
}

extern "C" void kernel_launch(void* const* d_in, const int* in_sizes, int n_in,
                              void* d_out, int out_size, void* d_ws, size_t ws_size,
                              hipStream_t stream) {
    const float* pred  = (const float*)d_in[0];
    const float* gt    = (const float*)d_in[1];
    const float* sigma = (const float*)d_in[2];
    float* out = (float*)d_out;

    float* partials = (float*)d_ws;   // up to B/ROWS_PER_BLOCK floats

    const int B = in_sizes[0] / NCOLS;                              // 8192
    const int nblocks = (B + ROWS_PER_BLOCK - 1) / ROWS_PER_BLOCK;  // 512

    gauss_quad_kernel<<<nblocks, TPB, 0, stream>>>(
        (const f32x4*)pred, (const f32x4*)gt, sigma, partials, B);
    gauss_finalize_kernel<<<1, 1024, 0, stream>>>(partials, sigma, out, B, nblocks);
}